// Round 6
// baseline (279.402 us; speedup 1.0000x reference)
//
#include <hip/hip_runtime.h>

#define B_SZ 16384
#define DIN  1024
#define HID  512
#define COMP 64

typedef __bf16 bf16_t;
typedef __bf16 bf16x4 __attribute__((ext_vector_type(4)));
typedef __bf16 bf16x8 __attribute__((ext_vector_type(8)));
typedef float  f32x4  __attribute__((ext_vector_type(4)));

__device__ __forceinline__ void gl2lds16(const void* g, void* l) {
    __builtin_amdgcn_global_load_lds(
        (const __attribute__((address_space(1))) void*)g,
        (__attribute__((address_space(3))) void*)l, 16, 0, 0);
}

// ---------------------------------------------------------------------------
// fused prep:
//   [0,1024)    : Wb transpose -> bf16 [512][1024]  (x2 branches)
//   [1024,1088) : Wc transpose -> bf16 [64][512]    (x2 branches)
//   [1088,1104) : prepG
//   [1104,3152) : init f1/f2 with bias bc (atomic accumulation target)
// ---------------------------------------------------------------------------
__global__ __launch_bounds__(256) void k_prep(
    const float* __restrict__ Wb1, const float* __restrict__ Wb2,
    bf16_t* __restrict__ wbt1, bf16_t* __restrict__ wbt2,
    const float* __restrict__ Wc1, const float* __restrict__ Wc2,
    bf16_t* __restrict__ wct1, bf16_t* __restrict__ wct2,
    const float* __restrict__ Wf1, const float* __restrict__ bf1v,
    const float* __restrict__ Wf2, const float* __restrict__ bf2v,
    const float* __restrict__ bc1, const float* __restrict__ bc2,
    float* __restrict__ f1, float* __restrict__ f2,
    float* __restrict__ G, float* __restrict__ c)
{
    const int bid = blockIdx.x, tid = threadIdx.x;
    __shared__ float tile[32][33];
    const int tx = tid & 31, ty = tid >> 5;

    if (bid < 1024) {                     // Wb transpose: K=1024, N=512
        const int z = bid >> 9, t = bid & 511;
        const float* in  = z ? Wb2  : Wb1;
        bf16_t*      out = z ? wbt2 : wbt1;
        const int n0 = (t & 15) * 32, k0 = (t >> 4) * 32;
        #pragma unroll
        for (int i = 0; i < 4; i++)
            tile[ty + i * 8][tx] = in[(size_t)(k0 + ty + i * 8) * HID + n0 + tx];
        __syncthreads();
        #pragma unroll
        for (int i = 0; i < 4; i++)
            out[(size_t)(n0 + ty + i * 8) * DIN + k0 + tx] = (bf16_t)tile[tx][ty + i * 8];
    } else if (bid < 1088) {              // Wc transpose: K=512, N=64
        const int l = bid - 1024;
        const int z = l >> 5, t = l & 31;
        const float* in  = z ? Wc2  : Wc1;
        bf16_t*      out = z ? wct2 : wct1;
        const int n0 = (t & 1) * 32, k0 = (t >> 1) * 32;
        #pragma unroll
        for (int i = 0; i < 4; i++)
            tile[ty + i * 8][tx] = in[(size_t)(k0 + ty + i * 8) * COMP + n0 + tx];
        __syncthreads();
        #pragma unroll
        for (int i = 0; i < 4; i++)
            out[(size_t)(n0 + ty + i * 8) * HID + k0 + tx] = (bf16_t)tile[tx][ty + i * 8];
    } else if (bid < 1104) {              // prepG
        const int i = (bid - 1088) * 256 + tid;   // 0..4095
        float a0 = 0.f, a1 = 0.f;
        #pragma unroll 8
        for (int o = 0; o < 64; o++) {
            float w = Wf1[(size_t)i * 64 + o];
            a0 = fmaf(w, Wf2[o * 2 + 0], a0);
            a1 = fmaf(w, Wf2[o * 2 + 1], a1);
        }
        G[i]        = a0;
        G[4096 + i] = a1;
        if (i < 2) {
            float s = bf2v[i];
            for (int o = 0; o < 64; o++) s = fmaf(bf1v[o], Wf2[o * 2 + i], s);
            c[i] = s;
        }
    } else {                              // F init with bias
        const int l = bid - 1104;         // 0..2047
        const int z = l >> 10;
        const float* bc = z ? bc2 : bc1;
        float*       f  = z ? f2  : f1;
        const int i = (l & 1023) * 256 + tid;
        const int c4 = (i & 15) * 4;
        float4 v = make_float4(bc[c4], bc[c4 + 1], bc[c4 + 2], bc[c4 + 3]);
        reinterpret_cast<float4*>(f)[i] = v;
    }
}

// ---------------------------------------------------------------------------
// GEMM1 fused: F += (relu(X @ Wb + bb)) @ Wc   (F pre-initialized with bc)
// R4 K-loop structure (77 us) but WITHOUT the XB prepass:
//  - B: bf16 via global_load_lds width=16, unpadded [128][32] (R4-exact)
//  - A: producer-side fp32->bf16 convert with REGISTER PREFETCH: X(k+1)
//    loaded into 4xfloat4 VGPRs during the MFMA phase of iter k; iter-top
//    does only cvt + ds_write_b64 (short VALU) before the barrier.
// XCD swizzle: 4 n-blocks of one (m,z) group share an XCD (X slab in L2).
// Epilogue: acc -> relu/bf16 -> LDS -> MFMA vs Wc -> unsafeAtomicAdd F.
// ---------------------------------------------------------------------------
__global__ __launch_bounds__(256) void k_gemm1f(
    const float* __restrict__ X1, const float* __restrict__ X2,
    const bf16_t* __restrict__ WT1, const bf16_t* __restrict__ WT2,
    const float* __restrict__ bias1, const float* __restrict__ bias2,
    const bf16_t* __restrict__ WC1, const bf16_t* __restrict__ WC2,
    float* __restrict__ F1, float* __restrict__ F2)
{
    const int bid = blockIdx.x;
    const int xcd = bid & 7, s = bid >> 3;
    const int nb = s & 3;
    const int G  = (s >> 2) * 8 + xcd;    // (m,z) group id, 0..255
    const int mb = G >> 1, z = G & 1;

    const float*  X    = z ? X2    : X1;
    const bf16_t* WT   = z ? WT2   : WT1;
    const float*  bias = z ? bias2 : bias1;
    const bf16_t* WC   = z ? WC2   : WC1;
    float*        F    = z ? F2    : F1;

    const int m0 = mb * 128;
    const int n0 = nb * 128;

    __shared__ char smem[17408];
    bf16_t* As = (bf16_t*)smem;            // [128][32] unpadded
    bf16_t* Bs = (bf16_t*)(smem + 8192);   // [128][32] unpadded
    bf16_t* Hs = (bf16_t*)smem;            // [64][136] epilogue alias

    const int tid  = threadIdx.x;
    const int lane = tid & 63;
    const int wave = tid >> 6;
    const int wr   = (wave >> 1) * 64;
    const int wc   = (wave & 1) * 64;
    const int l15  = lane & 15;
    const int g4   = lane >> 4;
    const int lk   = g4 * 8;

    // A-chunk ownership: chunk cc = i*256+tid -> row = cc>>3, q = cc&7
    int arow[4], aq[4];
    const float* aptr[4];
    #pragma unroll
    for (int i = 0; i < 4; i++) {
        int cc = i * 256 + tid;
        arow[i] = cc >> 3; aq[i] = cc & 7;
        aptr[i] = &X[(size_t)(m0 + arow[i]) * DIN + aq[i] * 4];
    }

    f32x4 acc[4][4] = {};
    float4 xv[4];

    // prologue: load X(k0=0)
    #pragma unroll
    for (int i = 0; i < 4; i++)
        xv[i] = *reinterpret_cast<const float4*>(aptr[i]);

    for (int k0 = 0; k0 < DIN; k0 += 32) {
        // B: async global->LDS (in flight during A cvt/write)
        #pragma unroll
        for (int i = 0; i < 2; i++) {
            int cc = i * 256 + tid;
            int r = cc >> 2, kh = (cc & 3) * 8;
            gl2lds16(&WT[(size_t)(n0 + r) * DIN + k0 + kh], &Bs[cc * 8]);
        }
        // A: cvt held regs -> LDS (producer side, off the LDS->MFMA path)
        #pragma unroll
        for (int i = 0; i < 4; i++) {
            bf16x4 bv;
            bv[0] = (bf16_t)xv[i].x; bv[1] = (bf16_t)xv[i].y;
            bv[2] = (bf16_t)xv[i].z; bv[3] = (bf16_t)xv[i].w;
            *reinterpret_cast<bf16x4*>(&As[arow[i] * 32 + aq[i] * 4]) = bv;
        }
        __syncthreads();

        bf16x8 af[4], bfv[4];
        #pragma unroll
        for (int mi = 0; mi < 4; mi++)
            af[mi] = *reinterpret_cast<const bf16x8*>(&As[(wr + mi * 16 + l15) * 32 + lk]);
        #pragma unroll
        for (int ni = 0; ni < 4; ni++)
            bfv[ni] = *reinterpret_cast<const bf16x8*>(&Bs[(wc + ni * 16 + l15) * 32 + lk]);

        // prefetch X(k+1) into regs — overlaps the MFMA block below
        int knext = (k0 + 32 < DIN) ? (k0 + 32) : 0;
        #pragma unroll
        for (int i = 0; i < 4; i++)
            xv[i] = *reinterpret_cast<const float4*>(aptr[i] + knext);

        #pragma unroll
        for (int mi = 0; mi < 4; mi++)
            #pragma unroll
            for (int ni = 0; ni < 4; ni++)
                acc[mi][ni] = __builtin_amdgcn_mfma_f32_16x16x32_bf16(
                    af[mi], bfv[ni], acc[mi][ni], 0, 0, 0);
        __syncthreads();
    }

    // ---- fused epilogue: H-half -> LDS -> (H @ Wc[n0:n0+128,:]) -> atomic F
    const int myhalf = wave >> 1;
    #pragma unroll
    for (int h = 0; h < 2; h++) {
        if (h) __syncthreads();
        if (myhalf == h) {
            #pragma unroll
            for (int mi = 0; mi < 4; mi++) {
                int lr = mi * 16 + g4 * 4;
                #pragma unroll
                for (int ni = 0; ni < 4; ni++) {
                    int colL = wc + ni * 16 + l15;
                    float bv = bias[n0 + colL];
                    #pragma unroll
                    for (int r = 0; r < 4; r++) {
                        float v = fmaxf(acc[mi][ni][r] + bv, 0.0f);
                        Hs[(lr + r) * 136 + colL] = (bf16_t)v;
                    }
                }
            }
        }
        __syncthreads();
        f32x4 acc2[4] = {};
        #pragma unroll
        for (int kk = 0; kk < 128; kk += 32) {
            bf16x8 af = *reinterpret_cast<const bf16x8*>(
                &Hs[(wave * 16 + l15) * 136 + kk + lk]);
            #pragma unroll
            for (int ni = 0; ni < 4; ni++) {
                bf16x8 bw = *reinterpret_cast<const bf16x8*>(
                    &WC[(size_t)(ni * 16 + l15) * HID + n0 + kk + lk]);
                acc2[ni] = __builtin_amdgcn_mfma_f32_16x16x32_bf16(
                    af, bw, acc2[ni], 0, 0, 0);
            }
        }
        int rbase = m0 + h * 64 + wave * 16 + g4 * 4;
        #pragma unroll
        for (int ni = 0; ni < 4; ni++) {
            int col = ni * 16 + l15;
            #pragma unroll
            for (int r = 0; r < 4; r++)
                unsafeAtomicAdd(&F[(size_t)(rbase + r) * COMP + col], acc2[ni][r]);
        }
    }
}

// ---------------------------------------------------------------------------
// bilinear: out[b][j] = f2[b] . G_j . f1[b]^T + c[j]
// ---------------------------------------------------------------------------
__global__ __launch_bounds__(256) void k_bilinear(
    const float* __restrict__ f1, const float* __restrict__ f2,
    const float* __restrict__ G, const float* __restrict__ c,
    float* __restrict__ out)
{
    __shared__ float Gs[2][4096];
    const int tid = threadIdx.x;
    for (int i = tid; i < 2048; i += 256)
        reinterpret_cast<float4*>(&Gs[0][0])[i] =
            reinterpret_cast<const float4*>(G)[i];
    const float c0 = c[0], c1 = c[1];
    __syncthreads();

    const int lane = tid & 63;
    const int wave = tid >> 6;
    const int base = (blockIdx.x * 4 + wave) * 4;

    for (int s = 0; s < 4; s++) {
        const int b = base + s;
        const float f1q = f1[(size_t)b * 64 + lane];
        const float f2q = f2[(size_t)b * 64 + lane];
        float a0 = 0.f, a1 = 0.f;
        #pragma unroll 8
        for (int p = 0; p < 64; p++) {
            float s2 = __shfl(f2q, p);
            a0 = fmaf(s2, Gs[0][p * 64 + lane], a0);
            a1 = fmaf(s2, Gs[1][p * 64 + lane], a1);
        }
        a0 *= f1q;
        a1 *= f1q;
        #pragma unroll
        for (int off = 32; off > 0; off >>= 1) {
            a0 += __shfl_xor(a0, off);
            a1 += __shfl_xor(a1, off);
        }
        if (lane == 0) {
            out[(size_t)b * 2 + 0] = a0 + c0;
            out[(size_t)b * 2 + 1] = a1 + c1;
        }
    }
}

// ---------------------------------------------------------------------------
extern "C" void kernel_launch(void* const* d_in, const int* in_sizes, int n_in,
                              void* d_out, int out_size, void* d_ws, size_t ws_size,
                              hipStream_t stream)
{
    const float* x1  = (const float*)d_in[0];
    const float* x2  = (const float*)d_in[1];
    const float* Wb1 = (const float*)d_in[2];
    const float* bb1 = (const float*)d_in[3];
    const float* Wb2 = (const float*)d_in[4];
    const float* bb2 = (const float*)d_in[5];
    const float* Wc1 = (const float*)d_in[6];
    const float* bc1 = (const float*)d_in[7];
    const float* Wc2 = (const float*)d_in[8];
    const float* bc2 = (const float*)d_in[9];
    const float* Wf1 = (const float*)d_in[10];
    const float* bf1v = (const float*)d_in[11];
    const float* Wf2 = (const float*)d_in[12];
    const float* bf2v = (const float*)d_in[13];
    float* out = (float*)d_out;

    // workspace carve-up (~10.2 MB — small ws keeps harness re-poison cheap)
    char* ws = (char*)d_ws;
    bf16_t* wbt1 = (bf16_t*)ws; ws += (size_t)HID * DIN * 2;
    bf16_t* wbt2 = (bf16_t*)ws; ws += (size_t)HID * DIN * 2;
    bf16_t* wct1 = (bf16_t*)ws; ws += (size_t)COMP * HID * 2;
    bf16_t* wct2 = (bf16_t*)ws; ws += (size_t)COMP * HID * 2;
    float*  f1   = (float*)ws;  ws += (size_t)B_SZ * COMP * 4;
    float*  f2   = (float*)ws;  ws += (size_t)B_SZ * COMP * 4;
    float*  G    = (float*)ws;  ws += (size_t)2 * 4096 * 4;
    float*  c    = (float*)ws;  ws += 256;

    k_prep<<<3152, 256, 0, stream>>>(Wb1, Wb2, wbt1, wbt2,
                                     Wc1, Wc2, wct1, wct2,
                                     Wf1, bf1v, Wf2, bf2v,
                                     bc1, bc2, f1, f2, G, c);
    k_gemm1f<<<1024, 256, 0, stream>>>(x1, x2, wbt1, wbt2, bb1, bb2,
                                       wct1, wct2, f1, f2);
    k_bilinear<<<1024, 256, 0, stream>>>(f1, f2, G, c, out);
}

// Round 7
// 266.049 us; speedup vs baseline: 1.0502x; 1.0502x over previous
//
#include <hip/hip_runtime.h>

#define B_SZ 16384
#define DIN  1024
#define HID  512
#define COMP 64

typedef __bf16 bf16_t;
typedef __bf16 bf16x4 __attribute__((ext_vector_type(4)));
typedef __bf16 bf16x8 __attribute__((ext_vector_type(8)));
typedef float  f32x4  __attribute__((ext_vector_type(4)));

__device__ __forceinline__ void gl2lds16(const void* g, void* l) {
    __builtin_amdgcn_global_load_lds(
        (const __attribute__((address_space(1))) void*)g,
        (__attribute__((address_space(3))) void*)l, 16, 0, 0);
}

// ---------------------------------------------------------------------------
// fused prep:
//   [0,1024)      : Wb transpose -> bf16 [512][1024]  (x2 branches)
//   [1024,1088)   : Wc transpose -> bf16 [64][512]    (x2 branches)
//   [1088,1104)   : prepG
//   [1104,3152)   : init f1/f2 with bias bc (atomic accumulation target)
//   [3152,19536)  : convert X fp32 -> bf16 row-major (x2 branches)
// ---------------------------------------------------------------------------
__global__ __launch_bounds__(256) void k_prep(
    const float* __restrict__ Wb1, const float* __restrict__ Wb2,
    bf16_t* __restrict__ wbt1, bf16_t* __restrict__ wbt2,
    const float* __restrict__ Wc1, const float* __restrict__ Wc2,
    bf16_t* __restrict__ wct1, bf16_t* __restrict__ wct2,
    const float* __restrict__ Wf1, const float* __restrict__ bf1v,
    const float* __restrict__ Wf2, const float* __restrict__ bf2v,
    const float* __restrict__ bc1, const float* __restrict__ bc2,
    float* __restrict__ f1, float* __restrict__ f2,
    const float* __restrict__ x1, const float* __restrict__ x2,
    bf16_t* __restrict__ xb1, bf16_t* __restrict__ xb2,
    float* __restrict__ G, float* __restrict__ c)
{
    const int bid = blockIdx.x, tid = threadIdx.x;

    if (bid >= 3152) {                    // X convert (bulk of the grid)
        const int l = bid - 3152;         // 0..16383
        const int z = l >> 13;
        const float* x  = z ? x2  : x1;
        bf16_t*      xb = z ? xb2 : xb1;
        const size_t base = ((size_t)(l & 8191) * 256 + tid) * 8;
        float4 v0 = *reinterpret_cast<const float4*>(x + base);
        float4 v1 = *reinterpret_cast<const float4*>(x + base + 4);
        bf16x8 o;
        o[0] = (bf16_t)v0.x; o[1] = (bf16_t)v0.y;
        o[2] = (bf16_t)v0.z; o[3] = (bf16_t)v0.w;
        o[4] = (bf16_t)v1.x; o[5] = (bf16_t)v1.y;
        o[6] = (bf16_t)v1.z; o[7] = (bf16_t)v1.w;
        *reinterpret_cast<bf16x8*>(xb + base) = o;
        return;
    }

    __shared__ float tile[32][33];
    const int tx = tid & 31, ty = tid >> 5;

    if (bid < 1024) {                     // Wb transpose: K=1024, N=512
        const int z = bid >> 9, t = bid & 511;
        const float* in  = z ? Wb2  : Wb1;
        bf16_t*      out = z ? wbt2 : wbt1;
        const int n0 = (t & 15) * 32, k0 = (t >> 4) * 32;
        #pragma unroll
        for (int i = 0; i < 4; i++)
            tile[ty + i * 8][tx] = in[(size_t)(k0 + ty + i * 8) * HID + n0 + tx];
        __syncthreads();
        #pragma unroll
        for (int i = 0; i < 4; i++)
            out[(size_t)(n0 + ty + i * 8) * DIN + k0 + tx] = (bf16_t)tile[tx][ty + i * 8];
    } else if (bid < 1088) {              // Wc transpose: K=512, N=64
        const int l = bid - 1024;
        const int z = l >> 5, t = l & 31;
        const float* in  = z ? Wc2  : Wc1;
        bf16_t*      out = z ? wct2 : wct1;
        const int n0 = (t & 1) * 32, k0 = (t >> 1) * 32;
        #pragma unroll
        for (int i = 0; i < 4; i++)
            tile[ty + i * 8][tx] = in[(size_t)(k0 + ty + i * 8) * COMP + n0 + tx];
        __syncthreads();
        #pragma unroll
        for (int i = 0; i < 4; i++)
            out[(size_t)(n0 + ty + i * 8) * HID + k0 + tx] = (bf16_t)tile[tx][ty + i * 8];
    } else if (bid < 1104) {              // prepG
        const int i = (bid - 1088) * 256 + tid;   // 0..4095
        float a0 = 0.f, a1 = 0.f;
        #pragma unroll 8
        for (int o = 0; o < 64; o++) {
            float w = Wf1[(size_t)i * 64 + o];
            a0 = fmaf(w, Wf2[o * 2 + 0], a0);
            a1 = fmaf(w, Wf2[o * 2 + 1], a1);
        }
        G[i]        = a0;
        G[4096 + i] = a1;
        if (i < 2) {
            float s = bf2v[i];
            for (int o = 0; o < 64; o++) s = fmaf(bf1v[o], Wf2[o * 2 + i], s);
            c[i] = s;
        }
    } else {                              // F init with bias
        const int l = bid - 1104;         // 0..2047
        const int z = l >> 10;
        const float* bc = z ? bc2 : bc1;
        float*       f  = z ? f2  : f1;
        const int i = (l & 1023) * 256 + tid;
        const int c4 = (i & 15) * 4;
        float4 v = make_float4(bc[c4], bc[c4 + 1], bc[c4 + 2], bc[c4 + 3]);
        reinterpret_cast<float4*>(f)[i] = v;
    }
}

// ---------------------------------------------------------------------------
// GEMM1 fused: F += (relu(XB @ Wb + bb)) @ Wc   (F pre-initialized with bc)
// R4 staging (all bf16 via global_load_lds) but BK=64: four 8 KB sub-buffers
// (each [128][32], gl2lds-linear), 8 gl2lds/thread/iter, 16 iterations ->
// half the barrier-drain events, 2x MFMA per drain. k-halves processed
// sequentially so u1 ds_reads pipeline under u0 MFMAs (no extra barrier).
// XCD swizzle: 4 n-blocks of one (m,z) group share an XCD (XB slab in L2).
// Epilogue: acc -> relu/bf16 -> LDS -> MFMA vs Wc -> unsafeAtomicAdd F.
// ---------------------------------------------------------------------------
__global__ __launch_bounds__(256) void k_gemm1f(
    const bf16_t* __restrict__ XB1, const bf16_t* __restrict__ XB2,
    const bf16_t* __restrict__ WT1, const bf16_t* __restrict__ WT2,
    const float* __restrict__ bias1, const float* __restrict__ bias2,
    const bf16_t* __restrict__ WC1, const bf16_t* __restrict__ WC2,
    float* __restrict__ F1, float* __restrict__ F2)
{
    const int bid = blockIdx.x;
    const int xcd = bid & 7, s = bid >> 3;
    const int nb = s & 3;
    const int G  = (s >> 2) * 8 + xcd;    // (m,z) group id, 0..255
    const int mb = G >> 1, z = G & 1;

    const bf16_t* XB   = z ? XB2   : XB1;
    const bf16_t* WT   = z ? WT2   : WT1;
    const float*  bias = z ? bias2 : bias1;
    const bf16_t* WC   = z ? WC2   : WC1;
    float*        F    = z ? F2    : F1;

    const int m0 = mb * 128;
    const int n0 = nb * 128;

    __shared__ char smem[32768];
    bf16_t* As[2] = { (bf16_t*)smem,           (bf16_t*)(smem + 8192)  };
    bf16_t* Bs[2] = { (bf16_t*)(smem + 16384), (bf16_t*)(smem + 24576) };
    bf16_t* Hs    = (bf16_t*)smem;            // [64][136] epilogue alias

    const int tid  = threadIdx.x;
    const int lane = tid & 63;
    const int wave = tid >> 6;
    const int wr   = (wave >> 1) * 64;
    const int wc   = (wave & 1) * 64;
    const int l15  = lane & 15;
    const int g4   = lane >> 4;
    const int lk   = g4 * 8;

    f32x4 acc[4][4] = {};

    for (int k0 = 0; k0 < DIN; k0 += 64) {
        // stage BK=64: two k-halves, each 512 chunks/operand (2/thread)
        #pragma unroll
        for (int u = 0; u < 2; u++) {
            #pragma unroll
            for (int i = 0; i < 2; i++) {
                int cc = i * 256 + tid;
                int r = cc >> 2, kh = (cc & 3) * 8;
                gl2lds16(&XB[(size_t)(m0 + r) * DIN + k0 + u * 32 + kh], &As[u][cc * 8]);
                gl2lds16(&WT[(size_t)(n0 + r) * DIN + k0 + u * 32 + kh], &Bs[u][cc * 8]);
            }
        }
        __syncthreads();

        #pragma unroll
        for (int u = 0; u < 2; u++) {
            bf16x8 af[4], bfv[4];
            #pragma unroll
            for (int mi = 0; mi < 4; mi++)
                af[mi] = *reinterpret_cast<const bf16x8*>(
                    &As[u][(wr + mi * 16 + l15) * 32 + lk]);
            #pragma unroll
            for (int ni = 0; ni < 4; ni++)
                bfv[ni] = *reinterpret_cast<const bf16x8*>(
                    &Bs[u][(wc + ni * 16 + l15) * 32 + lk]);
            #pragma unroll
            for (int mi = 0; mi < 4; mi++)
                #pragma unroll
                for (int ni = 0; ni < 4; ni++)
                    acc[mi][ni] = __builtin_amdgcn_mfma_f32_16x16x32_bf16(
                        af[mi], bfv[ni], acc[mi][ni], 0, 0, 0);
        }
        __syncthreads();
    }

    // ---- fused epilogue: H-half -> LDS -> (H @ Wc[n0:n0+128,:]) -> atomic F
    const int myhalf = wave >> 1;
    #pragma unroll
    for (int h = 0; h < 2; h++) {
        if (h) __syncthreads();
        if (myhalf == h) {
            #pragma unroll
            for (int mi = 0; mi < 4; mi++) {
                int lr = mi * 16 + g4 * 4;
                #pragma unroll
                for (int ni = 0; ni < 4; ni++) {
                    int colL = wc + ni * 16 + l15;
                    float bv = bias[n0 + colL];
                    #pragma unroll
                    for (int r = 0; r < 4; r++) {
                        float v = fmaxf(acc[mi][ni][r] + bv, 0.0f);
                        Hs[(lr + r) * 136 + colL] = (bf16_t)v;
                    }
                }
            }
        }
        __syncthreads();
        f32x4 acc2[4] = {};
        #pragma unroll
        for (int kk = 0; kk < 128; kk += 32) {
            bf16x8 af = *reinterpret_cast<const bf16x8*>(
                &Hs[(wave * 16 + l15) * 136 + kk + lk]);
            #pragma unroll
            for (int ni = 0; ni < 4; ni++) {
                bf16x8 bw = *reinterpret_cast<const bf16x8*>(
                    &WC[(size_t)(ni * 16 + l15) * HID + n0 + kk + lk]);
                acc2[ni] = __builtin_amdgcn_mfma_f32_16x16x32_bf16(
                    af, bw, acc2[ni], 0, 0, 0);
            }
        }
        int rbase = m0 + h * 64 + wave * 16 + g4 * 4;
        #pragma unroll
        for (int ni = 0; ni < 4; ni++) {
            int col = ni * 16 + l15;
            #pragma unroll
            for (int r = 0; r < 4; r++)
                unsafeAtomicAdd(&F[(size_t)(rbase + r) * COMP + col], acc2[ni][r]);
        }
    }
}

// ---------------------------------------------------------------------------
// bilinear: out[b][j] = f2[b] . G_j . f1[b]^T + c[j]
// ---------------------------------------------------------------------------
__global__ __launch_bounds__(256) void k_bilinear(
    const float* __restrict__ f1, const float* __restrict__ f2,
    const float* __restrict__ G, const float* __restrict__ c,
    float* __restrict__ out)
{
    __shared__ float Gs[2][4096];
    const int tid = threadIdx.x;
    for (int i = tid; i < 2048; i += 256)
        reinterpret_cast<float4*>(&Gs[0][0])[i] =
            reinterpret_cast<const float4*>(G)[i];
    const float c0 = c[0], c1 = c[1];
    __syncthreads();

    const int lane = tid & 63;
    const int wave = tid >> 6;
    const int base = (blockIdx.x * 4 + wave) * 4;

    for (int s = 0; s < 4; s++) {
        const int b = base + s;
        const float f1q = f1[(size_t)b * 64 + lane];
        const float f2q = f2[(size_t)b * 64 + lane];
        float a0 = 0.f, a1 = 0.f;
        #pragma unroll 8
        for (int p = 0; p < 64; p++) {
            float s2 = __shfl(f2q, p);
            a0 = fmaf(s2, Gs[0][p * 64 + lane], a0);
            a1 = fmaf(s2, Gs[1][p * 64 + lane], a1);
        }
        a0 *= f1q;
        a1 *= f1q;
        #pragma unroll
        for (int off = 32; off > 0; off >>= 1) {
            a0 += __shfl_xor(a0, off);
            a1 += __shfl_xor(a1, off);
        }
        if (lane == 0) {
            out[(size_t)b * 2 + 0] = a0 + c0;
            out[(size_t)b * 2 + 1] = a1 + c1;
        }
    }
}

// ---------------------------------------------------------------------------
extern "C" void kernel_launch(void* const* d_in, const int* in_sizes, int n_in,
                              void* d_out, int out_size, void* d_ws, size_t ws_size,
                              hipStream_t stream)
{
    const float* x1  = (const float*)d_in[0];
    const float* x2  = (const float*)d_in[1];
    const float* Wb1 = (const float*)d_in[2];
    const float* bb1 = (const float*)d_in[3];
    const float* Wb2 = (const float*)d_in[4];
    const float* bb2 = (const float*)d_in[5];
    const float* Wc1 = (const float*)d_in[6];
    const float* bc1 = (const float*)d_in[7];
    const float* Wc2 = (const float*)d_in[8];
    const float* bc2 = (const float*)d_in[9];
    const float* Wf1 = (const float*)d_in[10];
    const float* bf1v = (const float*)d_in[11];
    const float* Wf2 = (const float*)d_in[12];
    const float* bf2v = (const float*)d_in[13];
    float* out = (float*)d_out;

    // workspace carve-up (~74.8 MB)
    char* ws = (char*)d_ws;
    bf16_t* wbt1 = (bf16_t*)ws; ws += (size_t)HID * DIN * 2;
    bf16_t* wbt2 = (bf16_t*)ws; ws += (size_t)HID * DIN * 2;
    bf16_t* wct1 = (bf16_t*)ws; ws += (size_t)COMP * HID * 2;
    bf16_t* wct2 = (bf16_t*)ws; ws += (size_t)COMP * HID * 2;
    bf16_t* xb1  = (bf16_t*)ws; ws += (size_t)B_SZ * DIN * 2;   // 32 MB
    bf16_t* xb2  = (bf16_t*)ws; ws += (size_t)B_SZ * DIN * 2;   // 32 MB
    float*  f1   = (float*)ws;  ws += (size_t)B_SZ * COMP * 4;
    float*  f2   = (float*)ws;  ws += (size_t)B_SZ * COMP * 4;
    float*  G    = (float*)ws;  ws += (size_t)2 * 4096 * 4;
    float*  c    = (float*)ws;  ws += 256;

    k_prep<<<19536, 256, 0, stream>>>(Wb1, Wb2, wbt1, wbt2,
                                      Wc1, Wc2, wct1, wct2,
                                      Wf1, bf1v, Wf2, bf2v,
                                      bc1, bc2, f1, f2,
                                      x1, x2, xb1, xb2, G, c);
    k_gemm1f<<<1024, 256, 0, stream>>>(xb1, xb2, wbt1, wbt2, bb1, bb2,
                                       wct1, wct2, f1, f2);
    k_bilinear<<<1024, 256, 0, stream>>>(f1, f2, G, c, out);
}

// Round 8
// 261.886 us; speedup vs baseline: 1.0669x; 1.0159x over previous
//
#include <hip/hip_runtime.h>

#define B_SZ 16384
#define DIN  1024
#define HID  512
#define COMP 64

typedef __bf16 bf16_t;
typedef __bf16 bf16x4 __attribute__((ext_vector_type(4)));
typedef __bf16 bf16x8 __attribute__((ext_vector_type(8)));
typedef float  f32x4  __attribute__((ext_vector_type(4)));

__device__ __forceinline__ void gl2lds16(const void* g, void* l) {
    __builtin_amdgcn_global_load_lds(
        (const __attribute__((address_space(1))) void*)g,
        (__attribute__((address_space(3))) void*)l, 16, 0, 0);
}

// ---------------------------------------------------------------------------
// fused prep:
//   [0,1024)      : Wb transpose -> bf16 [512][1024]  (x2 branches)
//   [1024,1088)   : Wc transpose -> bf16 [64][512]    (x2 branches)
//   [1088,1104)   : prepG
//   [1104,3152)   : init f1/f2 with bias bc (atomic accumulation target)
//   [3152,19536)  : convert X fp32 -> bf16 row-major (x2 branches)
// ---------------------------------------------------------------------------
__global__ __launch_bounds__(256) void k_prep(
    const float* __restrict__ Wb1, const float* __restrict__ Wb2,
    bf16_t* __restrict__ wbt1, bf16_t* __restrict__ wbt2,
    const float* __restrict__ Wc1, const float* __restrict__ Wc2,
    bf16_t* __restrict__ wct1, bf16_t* __restrict__ wct2,
    const float* __restrict__ Wf1, const float* __restrict__ bf1v,
    const float* __restrict__ Wf2, const float* __restrict__ bf2v,
    const float* __restrict__ bc1, const float* __restrict__ bc2,
    float* __restrict__ f1, float* __restrict__ f2,
    const float* __restrict__ x1, const float* __restrict__ x2,
    bf16_t* __restrict__ xb1, bf16_t* __restrict__ xb2,
    float* __restrict__ G, float* __restrict__ c)
{
    const int bid = blockIdx.x, tid = threadIdx.x;

    if (bid >= 3152) {                    // X convert (bulk of the grid)
        const int l = bid - 3152;         // 0..16383
        const int z = l >> 13;
        const float* x  = z ? x2  : x1;
        bf16_t*      xb = z ? xb2 : xb1;
        const size_t base = ((size_t)(l & 8191) * 256 + tid) * 8;
        float4 v0 = *reinterpret_cast<const float4*>(x + base);
        float4 v1 = *reinterpret_cast<const float4*>(x + base + 4);
        bf16x8 o;
        o[0] = (bf16_t)v0.x; o[1] = (bf16_t)v0.y;
        o[2] = (bf16_t)v0.z; o[3] = (bf16_t)v0.w;
        o[4] = (bf16_t)v1.x; o[5] = (bf16_t)v1.y;
        o[6] = (bf16_t)v1.z; o[7] = (bf16_t)v1.w;
        *reinterpret_cast<bf16x8*>(xb + base) = o;
        return;
    }

    __shared__ float tile[32][33];
    const int tx = tid & 31, ty = tid >> 5;

    if (bid < 1024) {                     // Wb transpose: K=1024, N=512
        const int z = bid >> 9, t = bid & 511;
        const float* in  = z ? Wb2  : Wb1;
        bf16_t*      out = z ? wbt2 : wbt1;
        const int n0 = (t & 15) * 32, k0 = (t >> 4) * 32;
        #pragma unroll
        for (int i = 0; i < 4; i++)
            tile[ty + i * 8][tx] = in[(size_t)(k0 + ty + i * 8) * HID + n0 + tx];
        __syncthreads();
        #pragma unroll
        for (int i = 0; i < 4; i++)
            out[(size_t)(n0 + ty + i * 8) * DIN + k0 + tx] = (bf16_t)tile[tx][ty + i * 8];
    } else if (bid < 1088) {              // Wc transpose: K=512, N=64
        const int l = bid - 1024;
        const int z = l >> 5, t = l & 31;
        const float* in  = z ? Wc2  : Wc1;
        bf16_t*      out = z ? wct2 : wct1;
        const int n0 = (t & 1) * 32, k0 = (t >> 1) * 32;
        #pragma unroll
        for (int i = 0; i < 4; i++)
            tile[ty + i * 8][tx] = in[(size_t)(k0 + ty + i * 8) * COMP + n0 + tx];
        __syncthreads();
        #pragma unroll
        for (int i = 0; i < 4; i++)
            out[(size_t)(n0 + ty + i * 8) * HID + k0 + tx] = (bf16_t)tile[tx][ty + i * 8];
    } else if (bid < 1104) {              // prepG
        const int i = (bid - 1088) * 256 + tid;   // 0..4095
        float a0 = 0.f, a1 = 0.f;
        #pragma unroll 8
        for (int o = 0; o < 64; o++) {
            float w = Wf1[(size_t)i * 64 + o];
            a0 = fmaf(w, Wf2[o * 2 + 0], a0);
            a1 = fmaf(w, Wf2[o * 2 + 1], a1);
        }
        G[i]        = a0;
        G[4096 + i] = a1;
        if (i < 2) {
            float s = bf2v[i];
            for (int o = 0; o < 64; o++) s = fmaf(bf1v[o], Wf2[o * 2 + i], s);
            c[i] = s;
        }
    } else {                              // F init with bias
        const int l = bid - 1104;         // 0..2047
        const int z = l >> 10;
        const float* bc = z ? bc2 : bc1;
        float*       f  = z ? f2  : f1;
        const int i = (l & 1023) * 256 + tid;
        const int c4 = (i & 15) * 4;
        float4 v = make_float4(bc[c4], bc[c4 + 1], bc[c4 + 2], bc[c4 + 3]);
        reinterpret_cast<float4*>(f)[i] = v;
    }
}

// ---------------------------------------------------------------------------
// GEMM1 fused: F += (relu(XB @ Wb + bb)) @ Wc   (F pre-initialized with bc)
// K-loop: R7 BK=64, all-bf16 global_load_lds staging (measured-best).
// Epilogue REBUILT single-phase: all waves write relu(H) into Hs[128][132]
// (stride 132: 4*66 = 8 mod 32 -> quad-rows on disjoint bank octets), ONE
// barrier, each wave computes a 32x64 F-slice (2x4 frags) and atomically
// adds once. Replaces the old 2-pass myhalf scheme (5 barriers, idle waves,
// ~22K cyc/block — the measured iter-count-independent excess).
// ---------------------------------------------------------------------------
__global__ __launch_bounds__(256) void k_gemm1f(
    const bf16_t* __restrict__ XB1, const bf16_t* __restrict__ XB2,
    const bf16_t* __restrict__ WT1, const bf16_t* __restrict__ WT2,
    const float* __restrict__ bias1, const float* __restrict__ bias2,
    const bf16_t* __restrict__ WC1, const bf16_t* __restrict__ WC2,
    float* __restrict__ F1, float* __restrict__ F2)
{
    const int bid = blockIdx.x;
    const int xcd = bid & 7, s = bid >> 3;
    const int nb = s & 3;
    const int G  = (s >> 2) * 8 + xcd;    // (m,z) group id, 0..255
    const int mb = G >> 1, z = G & 1;

    const bf16_t* XB   = z ? XB2   : XB1;
    const bf16_t* WT   = z ? WT2   : WT1;
    const float*  bias = z ? bias2 : bias1;
    const bf16_t* WC   = z ? WC2   : WC1;
    float*        F    = z ? F2    : F1;

    const int m0 = mb * 128;
    const int n0 = nb * 128;

    __shared__ char smem[33792];
    bf16_t* As[2] = { (bf16_t*)smem,           (bf16_t*)(smem + 8192)  };
    bf16_t* Bs[2] = { (bf16_t*)(smem + 16384), (bf16_t*)(smem + 24576) };
    bf16_t* Hs    = (bf16_t*)smem;            // [128][132] epilogue alias

    const int tid  = threadIdx.x;
    const int lane = tid & 63;
    const int wave = tid >> 6;
    const int wr   = (wave >> 1) * 64;
    const int wc   = (wave & 1) * 64;
    const int l15  = lane & 15;
    const int g4   = lane >> 4;
    const int lk   = g4 * 8;

    f32x4 acc[4][4] = {};

    for (int k0 = 0; k0 < DIN; k0 += 64) {
        // stage BK=64: two k-halves, each 512 chunks/operand (2/thread)
        #pragma unroll
        for (int u = 0; u < 2; u++) {
            #pragma unroll
            for (int i = 0; i < 2; i++) {
                int cc = i * 256 + tid;
                int r = cc >> 2, kh = (cc & 3) * 8;
                gl2lds16(&XB[(size_t)(m0 + r) * DIN + k0 + u * 32 + kh], &As[u][cc * 8]);
                gl2lds16(&WT[(size_t)(n0 + r) * DIN + k0 + u * 32 + kh], &Bs[u][cc * 8]);
            }
        }
        __syncthreads();

        #pragma unroll
        for (int u = 0; u < 2; u++) {
            bf16x8 af[4], bfv[4];
            #pragma unroll
            for (int mi = 0; mi < 4; mi++)
                af[mi] = *reinterpret_cast<const bf16x8*>(
                    &As[u][(wr + mi * 16 + l15) * 32 + lk]);
            #pragma unroll
            for (int ni = 0; ni < 4; ni++)
                bfv[ni] = *reinterpret_cast<const bf16x8*>(
                    &Bs[u][(wc + ni * 16 + l15) * 32 + lk]);
            #pragma unroll
            for (int mi = 0; mi < 4; mi++)
                #pragma unroll
                for (int ni = 0; ni < 4; ni++)
                    acc[mi][ni] = __builtin_amdgcn_mfma_f32_16x16x32_bf16(
                        af[mi], bfv[ni], acc[mi][ni], 0, 0, 0);
        }
        __syncthreads();   // also protects As/Bs before the Hs alias write
    }

    // ---- epilogue phase 1: all waves write relu(H + bias) into Hs
    float bv[4];
    #pragma unroll
    for (int ni = 0; ni < 4; ni++)
        bv[ni] = bias[n0 + wc + ni * 16 + l15];
    #pragma unroll
    for (int mi = 0; mi < 4; mi++) {
        int lr = wr + mi * 16 + g4 * 4;
        #pragma unroll
        for (int ni = 0; ni < 4; ni++) {
            int colL = wc + ni * 16 + l15;
            #pragma unroll
            for (int r = 0; r < 4; r++) {
                float v = fmaxf(acc[mi][ni][r] + bv[ni], 0.0f);
                Hs[(lr + r) * 132 + colL] = (bf16_t)v;
            }
        }
    }
    __syncthreads();

    // ---- phase 2: each wave: F[m0+wave*32 .. +32][0:64] += Hs @ WC-slice
    f32x4 acc2[2][4] = {};
    #pragma unroll
    for (int kk = 0; kk < 128; kk += 32) {
        bf16x8 af[2];
        #pragma unroll
        for (int m2 = 0; m2 < 2; m2++)
            af[m2] = *reinterpret_cast<const bf16x8*>(
                &Hs[(wave * 32 + m2 * 16 + l15) * 132 + kk + lk]);
        #pragma unroll
        for (int ni = 0; ni < 4; ni++) {
            bf16x8 bw = *reinterpret_cast<const bf16x8*>(
                &WC[(size_t)(ni * 16 + l15) * HID + n0 + kk + lk]);
            #pragma unroll
            for (int m2 = 0; m2 < 2; m2++)
                acc2[m2][ni] = __builtin_amdgcn_mfma_f32_16x16x32_bf16(
                    af[m2], bw, acc2[m2][ni], 0, 0, 0);
        }
    }
    #pragma unroll
    for (int m2 = 0; m2 < 2; m2++) {
        int rbase = m0 + wave * 32 + m2 * 16 + g4 * 4;
        #pragma unroll
        for (int ni = 0; ni < 4; ni++) {
            int col = ni * 16 + l15;
            #pragma unroll
            for (int r = 0; r < 4; r++)
                unsafeAtomicAdd(&F[(size_t)(rbase + r) * COMP + col], acc2[m2][ni][r]);
        }
    }
}

// ---------------------------------------------------------------------------
// bilinear: out[b][j] = f2[b] . G_j . f1[b]^T + c[j]
// ---------------------------------------------------------------------------
__global__ __launch_bounds__(256) void k_bilinear(
    const float* __restrict__ f1, const float* __restrict__ f2,
    const float* __restrict__ G, const float* __restrict__ c,
    float* __restrict__ out)
{
    __shared__ float Gs[2][4096];
    const int tid = threadIdx.x;
    for (int i = tid; i < 2048; i += 256)
        reinterpret_cast<float4*>(&Gs[0][0])[i] =
            reinterpret_cast<const float4*>(G)[i];
    const float c0 = c[0], c1 = c[1];
    __syncthreads();

    const int lane = tid & 63;
    const int wave = tid >> 6;
    const int base = (blockIdx.x * 4 + wave) * 4;

    for (int s = 0; s < 4; s++) {
        const int b = base + s;
        const float f1q = f1[(size_t)b * 64 + lane];
        const float f2q = f2[(size_t)b * 64 + lane];
        float a0 = 0.f, a1 = 0.f;
        #pragma unroll 8
        for (int p = 0; p < 64; p++) {
            float s2 = __shfl(f2q, p);
            a0 = fmaf(s2, Gs[0][p * 64 + lane], a0);
            a1 = fmaf(s2, Gs[1][p * 64 + lane], a1);
        }
        a0 *= f1q;
        a1 *= f1q;
        #pragma unroll
        for (int off = 32; off > 0; off >>= 1) {
            a0 += __shfl_xor(a0, off);
            a1 += __shfl_xor(a1, off);
        }
        if (lane == 0) {
            out[(size_t)b * 2 + 0] = a0 + c0;
            out[(size_t)b * 2 + 1] = a1 + c1;
        }
    }
}

// ---------------------------------------------------------------------------
extern "C" void kernel_launch(void* const* d_in, const int* in_sizes, int n_in,
                              void* d_out, int out_size, void* d_ws, size_t ws_size,
                              hipStream_t stream)
{
    const float* x1  = (const float*)d_in[0];
    const float* x2  = (const float*)d_in[1];
    const float* Wb1 = (const float*)d_in[2];
    const float* bb1 = (const float*)d_in[3];
    const float* Wb2 = (const float*)d_in[4];
    const float* bb2 = (const float*)d_in[5];
    const float* Wc1 = (const float*)d_in[6];
    const float* bc1 = (const float*)d_in[7];
    const float* Wc2 = (const float*)d_in[8];
    const float* bc2 = (const float*)d_in[9];
    const float* Wf1 = (const float*)d_in[10];
    const float* bf1v = (const float*)d_in[11];
    const float* Wf2 = (const float*)d_in[12];
    const float* bf2v = (const float*)d_in[13];
    float* out = (float*)d_out;

    // workspace carve-up (~74.8 MB)
    char* ws = (char*)d_ws;
    bf16_t* wbt1 = (bf16_t*)ws; ws += (size_t)HID * DIN * 2;
    bf16_t* wbt2 = (bf16_t*)ws; ws += (size_t)HID * DIN * 2;
    bf16_t* wct1 = (bf16_t*)ws; ws += (size_t)COMP * HID * 2;
    bf16_t* wct2 = (bf16_t*)ws; ws += (size_t)COMP * HID * 2;
    bf16_t* xb1  = (bf16_t*)ws; ws += (size_t)B_SZ * DIN * 2;   // 32 MB
    bf16_t* xb2  = (bf16_t*)ws; ws += (size_t)B_SZ * DIN * 2;   // 32 MB
    float*  f1   = (float*)ws;  ws += (size_t)B_SZ * COMP * 4;
    float*  f2   = (float*)ws;  ws += (size_t)B_SZ * COMP * 4;
    float*  G    = (float*)ws;  ws += (size_t)2 * 4096 * 4;
    float*  c    = (float*)ws;  ws += 256;

    k_prep<<<19536, 256, 0, stream>>>(Wb1, Wb2, wbt1, wbt2,
                                      Wc1, Wc2, wct1, wct2,
                                      Wf1, bf1v, Wf2, bf2v,
                                      bc1, bc2, f1, f2,
                                      x1, x2, xb1, xb2, G, c);
    k_gemm1f<<<1024, 256, 0, stream>>>(xb1, xb2, wbt1, wbt2, bb1, bb2,
                                       wct1, wct2, f1, f2);
    k_bilinear<<<1024, 256, 0, stream>>>(f1, f2, G, c, out);
}